// Round 4
// baseline (130.834 us; speedup 1.0000x reference)
//
#include <hip/hip_runtime.h>

#define D 64
#define ITEM_PAD 100000
#define LSEQ 200
#define BATCH 4096
#define NEG_W 0.1f
#define NBI 512                         // gram_item partial blocks
#define NBU 64                          // gram_user partial blocks
#define GSZ (D * D)                     // 4096
#define PITEM_OFF 0
#define PUSER_OFF ((size_t)NBI * GSZ)              // 2,097,152 floats
#define POS_OFF   (PUSER_OFF + (size_t)NBU * GSZ)  // 2,359,296
#define WS2_OFF   (POS_OFF + BATCH)                // 2,363,392
#define CTR_OFF   (WS2_OFF + 256)                  // counter (1 uint)

// ---------------------------------------------------------------------------
// Kernel A: all partials in ONE launch. No atomics, no pre-zeroed memory.
//   blocks [0, NBI)          : item-Gram partial (32-row chunks, reg prefetch)
//   blocks [NBI, NBI+NBU)    : user-Gram partial
//   blocks [NBI+NBU, +BATCH) : pos-loss row partial
// Block 0 thread 0 also zero-inits the kernel-B completion counter (ws is
// poisoned 0xAA before every launch; kernel boundary orders this vs B).
// ---------------------------------------------------------------------------
__global__ void fused_partials(const int* __restrict__ uids,
                               const int* __restrict__ pos_iids,
                               const float* __restrict__ user_W,
                               const float* __restrict__ item_W,
                               const float* __restrict__ h,
                               float* __restrict__ ws) {
    __shared__ float smem[32 * D];   // 8 KB; gram tile / pos scratch alias
    const int bid = blockIdx.x;
    const int t   = threadIdx.x;

    if (bid == 0 && t == 0) ((unsigned*)(ws + CTR_OFF))[0] = 0u;

    if (bid < NBI + NBU) {
        // ---- Gram partial: 4x4 acc per thread, 32-row chunks, prefetch ----
        const bool item = (bid < NBI);
        const float* __restrict__ W = item ? item_W : user_W;
        const int* __restrict__ idx = item ? nullptr : uids;
        const int nrows  = item ? (ITEM_PAD + 1) : BATCH;
        const int stride = item ? NBI : NBU;
        const int b0     = item ? bid : bid - NBI;
        float* __restrict__ out =
            ws + (item ? PITEM_OFF + (size_t)b0 * GSZ : PUSER_OFF + (size_t)b0 * GSZ);

        const int ti = t >> 4;      // 0..15
        const int tj = t & 15;
        float acc[4][4] = {{0.f,0.f,0.f,0.f},{0.f,0.f,0.f,0.f},
                           {0.f,0.f,0.f,0.f},{0.f,0.f,0.f,0.f}};

        const int nchunks = (nrows + 31) >> 5;

        // prefetch first chunk into registers
        float4 va = make_float4(0.f,0.f,0.f,0.f), vb = va;
        int c = b0;
        if (c < nchunks) {
            const int ra = (c << 5) + ti, rb = ra + 16;
            if (ra < nrows) {
                const int sa = idx ? idx[ra] : ra;
                va = *(const float4*)(W + (size_t)sa * D + tj * 4);
            }
            if (rb < nrows) {
                const int sb = idx ? idx[rb] : rb;
                vb = *(const float4*)(W + (size_t)sb * D + tj * 4);
            }
        }

        for (; c < nchunks; ) {
            __syncthreads();     // previous chunk's compute done
            *(float4*)(smem + ti * D + tj * 4)        = va;
            *(float4*)(smem + (ti + 16) * D + tj * 4) = vb;
            __syncthreads();

            const int cn = c + stride;
            va = make_float4(0.f,0.f,0.f,0.f); vb = va;
            if (cn < nchunks) {    // issue next chunk's loads before compute
                const int ra = (cn << 5) + ti, rb = ra + 16;
                if (ra < nrows) {
                    const int sa = idx ? idx[ra] : ra;
                    va = *(const float4*)(W + (size_t)sa * D + tj * 4);
                }
                if (rb < nrows) {
                    const int sb = idx ? idx[rb] : rb;
                    vb = *(const float4*)(W + (size_t)sb * D + tj * 4);
                }
            }

            #pragma unroll
            for (int r2 = 0; r2 < 32; ++r2) {
                float xi[4], xj[4];
                *(float4*)xi = *(const float4*)(smem + r2 * D + ti * 4);
                *(float4*)xj = *(const float4*)(smem + r2 * D + tj * 4);
                #pragma unroll
                for (int a = 0; a < 4; ++a)
                    #pragma unroll
                    for (int b2 = 0; b2 < 4; ++b2)
                        acc[a][b2] += xi[a] * xj[b2];
            }
            c = cn;
        }
        #pragma unroll
        for (int a = 0; a < 4; ++a)
            *(float4*)(out + (ti * 4 + a) * D + tj * 4) = *(const float4*)acc[a];
    } else {
        // ---- pos-loss row partial ----
        const int b = bid - (NBI + NBU);
        float* uh   = smem;                      // [64]
        int*   sidx = (int*)(smem + D);          // [200]
        float* red  = smem + D + LSEQ;           // [4]

        if (t < LSEQ) sidx[t] = pos_iids[(size_t)b * LSEQ + t];
        if (t >= 192) {
            const int j = t - 192;
            uh[j] = user_W[(size_t)uids[b] * D + j] * h[j];
        }
        __syncthreads();

        const int lane = t & 63;
        const int wave = t >> 6;
        const int p    = lane >> 4;      // 0..3
        const int q    = lane & 15;      // 0..15
        const int base = wave * 4 + p;   // 0..15

        const float4 u4 = *(const float4*)(uh + q * 4);

        int ids[13];
        #pragma unroll
        for (int k = 0; k < 13; ++k) {
            const int l = base + 16 * k;
            ids[k] = (l < LSEQ) ? sidx[l] : ITEM_PAD;
        }
        float4 rows[13];
        #pragma unroll
        for (int k = 0; k < 13; ++k) {
            float4 v = make_float4(0.f, 0.f, 0.f, 0.f);
            if (ids[k] != ITEM_PAD)
                v = *(const float4*)(item_W + (size_t)ids[k] * D + q * 4);
            rows[k] = v;
        }

        float local = 0.f;
        #pragma unroll
        for (int k = 0; k < 13; ++k) {
            float s = u4.x*rows[k].x + u4.y*rows[k].y + u4.z*rows[k].z + u4.w*rows[k].w;
            s += __shfl_xor(s, 1);
            s += __shfl_xor(s, 2);
            s += __shfl_xor(s, 4);
            s += __shfl_xor(s, 8);
            if (q == 0)
                local += (1.0f - NEG_W) * s * s - 2.0f * s;   // s==0 for masked/oob
        }
        local += __shfl_xor(local, 1);
        local += __shfl_xor(local, 2);
        local += __shfl_xor(local, 4);
        local += __shfl_xor(local, 8);
        local += __shfl_xor(local, 16);
        local += __shfl_xor(local, 32);
        if (lane == 0) red[wave] = local;
        __syncthreads();
        if (t == 0)
            ws[POS_OFF + b] = red[0] + red[1] + red[2] + red[3];
    }
}

// ---------------------------------------------------------------------------
// Kernel B: 256 blocks. Block b reduces k-slice [b*16, b*16+16) of Pitem/Puser,
// applies NEG_W * h_i * h_j, adds its 16 pos partials, writes ws2[b]; the
// LAST block to finish (device-scope counter + fences) sums ws2 -> out[0].
// ---------------------------------------------------------------------------
__global__ void reduce_final(const float* __restrict__ ws,
                             const float* __restrict__ h,
                             float* __restrict__ ws2,
                             unsigned* __restrict__ counter,
                             float* __restrict__ out) {
    __shared__ float rI[4][16];
    __shared__ float rU[4][16];
    __shared__ int isLast;
    const int b  = blockIdx.x;
    const int t  = threadIdx.x;
    const int kk = t & 15;
    const int ps = t >> 4;        // 0..15
    const int lane = t & 63;
    const int wave = t >> 6;
    const int k  = b * 16 + kk;

    float si = 0.f, su = 0.f;
    #pragma unroll 8
    for (int p = ps; p < NBI; p += 16) si += ws[PITEM_OFF + (size_t)p * GSZ + k];
    #pragma unroll
    for (int p = ps; p < NBU; p += 16) su += ws[PUSER_OFF + (size_t)p * GSZ + k];

    si += __shfl_xor(si, 16); si += __shfl_xor(si, 32);
    su += __shfl_xor(su, 16); su += __shfl_xor(su, 32);
    if (lane < 16) { rI[wave][kk] = si; rU[wave][kk] = su; }
    __syncthreads();

    float c = 0.f;
    if (t < 16) {
        const float Gi = rI[0][t] + rI[1][t] + rI[2][t] + rI[3][t];
        const float Gu = rU[0][t] + rU[1][t] + rU[2][t] + rU[3][t];
        const int kg = b * 16 + t;
        const int i = kg >> 6, j = kg & 63;
        c = NEG_W * Gi * Gu * h[i] * h[j] + ws[POS_OFF + b * 16 + t];
    }
    if (wave == 0) {
        c += __shfl_xor(c, 1);
        c += __shfl_xor(c, 2);
        c += __shfl_xor(c, 4);
        c += __shfl_xor(c, 8);
        if (lane == 0) ws2[b] = c;
    }

    // last-block final reduction
    if (t == 0) {
        __threadfence();                       // ws2[b] visible before signal
        const unsigned old = atomicAdd(counter, 1u);
        isLast = (old == 255u);
    }
    __syncthreads();
    if (isLast) {
        __threadfence();                       // acquire all ws2 writes
        float s = ws2[t];
        s += __shfl_xor(s, 1);
        s += __shfl_xor(s, 2);
        s += __shfl_xor(s, 4);
        s += __shfl_xor(s, 8);
        s += __shfl_xor(s, 16);
        s += __shfl_xor(s, 32);
        __shared__ float red[4];
        if (lane == 0) red[wave] = s;
        __syncthreads();
        if (t == 0) out[0] = red[0] + red[1] + red[2] + red[3];
    }
}

extern "C" void kernel_launch(void* const* d_in, const int* in_sizes, int n_in,
                              void* d_out, int out_size, void* d_ws, size_t ws_size,
                              hipStream_t stream) {
    const int*   uids     = (const int*)d_in[0];
    const int*   pos_iids = (const int*)d_in[1];
    const float* user_W   = (const float*)d_in[2];
    const float* item_W   = (const float*)d_in[3];
    const float* h        = (const float*)d_in[4];
    float* out = (float*)d_out;
    float* ws  = (float*)d_ws;

    fused_partials<<<NBI + NBU + BATCH, 256, 0, stream>>>(uids, pos_iids, user_W,
                                                          item_W, h, ws);
    reduce_final<<<256, 256, 0, stream>>>(ws, h, ws + WS2_OFF,
                                          (unsigned*)(ws + CTR_OFF), out);
}

// Round 5
// 122.919 us; speedup vs baseline: 1.0644x; 1.0644x over previous
//
#include <hip/hip_runtime.h>

#define D 64
#define ITEM_PAD 100000
#define LSEQ 200
#define BATCH 4096
#define NEG_W 0.1f
#define NBI 512                         // gram_item partial blocks
#define NBU 64                          // gram_user partial blocks
#define GSZ (D * D)                     // 4096

// ws layout (floats):
//   [0, 3200032)  bf16 item table: 100001 rows x 64 bf16 (12.8 MB)
#define BFT_FLOATS 3200032
#define PITEM_OFF  ((size_t)BFT_FLOATS)
#define PUSER_OFF  (PITEM_OFF + (size_t)NBI * GSZ)
#define POS_OFF    (PUSER_OFF + (size_t)NBU * GSZ)
#define GDOT_OFF   (POS_OFF + BATCH)

__device__ __forceinline__ unsigned short f2bf_rne(float x) {
    unsigned u = __builtin_bit_cast(unsigned, x);
    return (unsigned short)((u + 0x7fffu + ((u >> 16) & 1u)) >> 16);
}
__device__ __forceinline__ float bf_lo(unsigned u) {
    return __builtin_bit_cast(float, u << 16);
}
__device__ __forceinline__ float bf_hi(unsigned u) {
    return __builtin_bit_cast(float, u & 0xffff0000u);
}

// ---------------------------------------------------------------------------
// Kernel A: Gram partials. Item blocks ALSO emit the bf16 item table (each
// item row is loaded exactly once across the striped chunks -> free convert).
//   blocks [0, NBI)       : item-Gram partial -> Pitem[blk]; bf16 table write
//   blocks [NBI, NBI+NBU) : user-Gram partial -> Puser[blk-NBI]
// 32-row LDS chunks with register prefetch of the next chunk.
// ---------------------------------------------------------------------------
__global__ void gram_convert(const int* __restrict__ uids,
                             const float* __restrict__ user_W,
                             const float* __restrict__ item_W,
                             float* __restrict__ ws) {
    __shared__ float smem[32 * D];   // 8 KB
    const int bid = blockIdx.x;
    const int t   = threadIdx.x;

    const bool item = (bid < NBI);
    const float* __restrict__ W = item ? item_W : user_W;
    const int* __restrict__ idx = item ? nullptr : uids;
    const int nrows  = item ? (ITEM_PAD + 1) : BATCH;
    const int stride = item ? NBI : NBU;
    const int b0     = item ? bid : bid - NBI;
    float* __restrict__ out =
        ws + (item ? PITEM_OFF + (size_t)b0 * GSZ : PUSER_OFF + (size_t)b0 * GSZ);
    unsigned short* __restrict__ bft = (unsigned short*)ws;

    const int ti = t >> 4;      // 0..15
    const int tj = t & 15;
    float acc[4][4] = {{0.f,0.f,0.f,0.f},{0.f,0.f,0.f,0.f},
                       {0.f,0.f,0.f,0.f},{0.f,0.f,0.f,0.f}};

    const int nchunks = (nrows + 31) >> 5;

    float4 va = make_float4(0.f,0.f,0.f,0.f), vb = va;
    int c = b0;
    if (c < nchunks) {
        const int ra = (c << 5) + ti, rb = ra + 16;
        if (ra < nrows) {
            const int sa = idx ? idx[ra] : ra;
            va = *(const float4*)(W + (size_t)sa * D + tj * 4);
        }
        if (rb < nrows) {
            const int sb = idx ? idx[rb] : rb;
            vb = *(const float4*)(W + (size_t)sb * D + tj * 4);
        }
    }

    while (c < nchunks) {
        __syncthreads();     // previous chunk's LDS reads done
        *(float4*)(smem + ti * D + tj * 4)        = va;
        *(float4*)(smem + (ti + 16) * D + tj * 4) = vb;

        if (item) {          // emit bf16 rows of the CURRENT chunk
            const int ra = (c << 5) + ti, rb = ra + 16;
            if (ra < nrows) {
                ushort4 s4 = { f2bf_rne(va.x), f2bf_rne(va.y),
                               f2bf_rne(va.z), f2bf_rne(va.w) };
                *(ushort4*)(bft + (size_t)ra * D + tj * 4) = s4;
            }
            if (rb < nrows) {
                ushort4 s4 = { f2bf_rne(vb.x), f2bf_rne(vb.y),
                               f2bf_rne(vb.z), f2bf_rne(vb.w) };
                *(ushort4*)(bft + (size_t)rb * D + tj * 4) = s4;
            }
        }
        __syncthreads();

        const int cn = c + stride;
        va = make_float4(0.f,0.f,0.f,0.f); vb = va;
        if (cn < nchunks) {    // prefetch next chunk before compute
            const int ra = (cn << 5) + ti, rb = ra + 16;
            if (ra < nrows) {
                const int sa = idx ? idx[ra] : ra;
                va = *(const float4*)(W + (size_t)sa * D + tj * 4);
            }
            if (rb < nrows) {
                const int sb = idx ? idx[rb] : rb;
                vb = *(const float4*)(W + (size_t)sb * D + tj * 4);
            }
        }

        #pragma unroll
        for (int r2 = 0; r2 < 32; ++r2) {
            float xi[4], xj[4];
            *(float4*)xi = *(const float4*)(smem + r2 * D + ti * 4);
            *(float4*)xj = *(const float4*)(smem + r2 * D + tj * 4);
            #pragma unroll
            for (int a = 0; a < 4; ++a)
                #pragma unroll
                for (int b2 = 0; b2 < 4; ++b2)
                    acc[a][b2] += xi[a] * xj[b2];
        }
        c = cn;
    }
    #pragma unroll
    for (int a = 0; a < 4; ++a)
        *(float4*)(out + (ti * 4 + a) * D + tj * 4) = *(const float4*)acc[a];
}

// ---------------------------------------------------------------------------
// Kernel B:
//   blocks [0, BATCH)         : pos-loss row partial from the bf16 table.
//       8 lanes x 16B (uint4 = 8 bf16) per row; 32 rows per wave-step;
//       3-step shuffle reduce. -> pos[b]
//   blocks [BATCH, BATCH+256) : gram-dot reduce: k-slice of Pitem/Puser,
//       apply NEG_W*h_i*h_j -> gdot[bb]
// ---------------------------------------------------------------------------
__global__ void pos_and_reduce(const int* __restrict__ uids,
                               const int* __restrict__ pos_iids,
                               const float* __restrict__ user_W,
                               const float* __restrict__ h,
                               float* __restrict__ ws) {
    const int bid = blockIdx.x;
    const int t   = threadIdx.x;
    const int lane = t & 63;
    const int wave = t >> 6;

    if (bid < BATCH) {
        // ---- pos-loss partial ----
        __shared__ float uh[D];
        __shared__ int   sidx[LSEQ];
        __shared__ float red[4];
        const int b = bid;
        const unsigned short* __restrict__ bft = (const unsigned short*)ws;

        if (t < LSEQ) sidx[t] = pos_iids[(size_t)b * LSEQ + t];
        if (t >= 192) {
            const int j = t - 192;
            uh[j] = user_W[(size_t)uids[b] * D + j] * h[j];
        }
        __syncthreads();

        const int p    = lane >> 3;      // 0..7  (row slot in wave)
        const int q    = lane & 7;       // 0..7  (8 d's per lane)
        const int base = wave * 8 + p;   // 0..31

        float u8[8];
        *(float4*)(u8 + 0) = *(const float4*)(uh + q * 8);
        *(float4*)(u8 + 4) = *(const float4*)(uh + q * 8 + 4);

        int ids[7];
        #pragma unroll
        for (int k = 0; k < 7; ++k) {
            const int l = base + 32 * k;
            ids[k] = (l < LSEQ) ? sidx[l] : ITEM_PAD;
        }
        uint4 rows[7];
        #pragma unroll
        for (int k = 0; k < 7; ++k) {
            uint4 v = make_uint4(0u, 0u, 0u, 0u);
            if (ids[k] != ITEM_PAD)
                v = *(const uint4*)(bft + (size_t)ids[k] * D + q * 8);
            rows[k] = v;
        }

        float local = 0.f;
        #pragma unroll
        for (int k = 0; k < 7; ++k) {
            const uint4 v = rows[k];
            float s = bf_lo(v.x)*u8[0] + bf_hi(v.x)*u8[1]
                    + bf_lo(v.y)*u8[2] + bf_hi(v.y)*u8[3]
                    + bf_lo(v.z)*u8[4] + bf_hi(v.z)*u8[5]
                    + bf_lo(v.w)*u8[6] + bf_hi(v.w)*u8[7];
            s += __shfl_xor(s, 1);
            s += __shfl_xor(s, 2);
            s += __shfl_xor(s, 4);
            if (q == 0)
                local += (1.0f - NEG_W) * s * s - 2.0f * s;   // s==0 for masked/oob
        }
        local += __shfl_xor(local, 1);
        local += __shfl_xor(local, 2);
        local += __shfl_xor(local, 4);
        local += __shfl_xor(local, 8);
        local += __shfl_xor(local, 16);
        local += __shfl_xor(local, 32);
        if (lane == 0) red[wave] = local;
        __syncthreads();
        if (t == 0)
            ws[POS_OFF + b] = red[0] + red[1] + red[2] + red[3];
    } else {
        // ---- gram-dot reduce ----
        __shared__ float rI[4][16];
        __shared__ float rU[4][16];
        const int bb = bid - BATCH;       // 0..255
        const int kk = t & 15;
        const int ps = t >> 4;            // 0..15
        const int k  = bb * 16 + kk;

        float si = 0.f, su = 0.f;
        #pragma unroll 8
        for (int p = ps; p < NBI; p += 16) si += ws[PITEM_OFF + (size_t)p * GSZ + k];
        #pragma unroll
        for (int p = ps; p < NBU; p += 16) su += ws[PUSER_OFF + (size_t)p * GSZ + k];

        si += __shfl_xor(si, 16); si += __shfl_xor(si, 32);
        su += __shfl_xor(su, 16); su += __shfl_xor(su, 32);
        if (lane < 16) { rI[wave][kk] = si; rU[wave][kk] = su; }
        __syncthreads();

        if (wave == 0) {
            float c = 0.f;
            if (t < 16) {
                const float Gi = rI[0][t] + rI[1][t] + rI[2][t] + rI[3][t];
                const float Gu = rU[0][t] + rU[1][t] + rU[2][t] + rU[3][t];
                const int kg = bb * 16 + t;
                const int i = kg >> 6, j = kg & 63;
                c = NEG_W * Gi * Gu * h[i] * h[j];
            }
            c += __shfl_xor(c, 1);
            c += __shfl_xor(c, 2);
            c += __shfl_xor(c, 4);
            c += __shfl_xor(c, 8);
            if (lane == 0) ws[GDOT_OFF + bb] = c;
        }
    }
}

// ---------------------------------------------------------------------------
// Kernel C: out[0] = sum(pos[0..4096)) + sum(gdot[0..256)).  4352 = 17*256.
// ---------------------------------------------------------------------------
__global__ void final_sum(const float* __restrict__ ws, float* __restrict__ out) {
    __shared__ float red[4];
    const int t = threadIdx.x;
    float s = 0.f;
    #pragma unroll
    for (int k = 0; k < 17; ++k)
        s += ws[POS_OFF + t + k * 256];   // POS_OFF..POS_OFF+4352 spans pos+gdot
    s += __shfl_xor(s, 1);
    s += __shfl_xor(s, 2);
    s += __shfl_xor(s, 4);
    s += __shfl_xor(s, 8);
    s += __shfl_xor(s, 16);
    s += __shfl_xor(s, 32);
    const int lane = t & 63, wave = t >> 6;
    if (lane == 0) red[wave] = s;
    __syncthreads();
    if (t == 0) out[0] = red[0] + red[1] + red[2] + red[3];
}

extern "C" void kernel_launch(void* const* d_in, const int* in_sizes, int n_in,
                              void* d_out, int out_size, void* d_ws, size_t ws_size,
                              hipStream_t stream) {
    const int*   uids     = (const int*)d_in[0];
    const int*   pos_iids = (const int*)d_in[1];
    const float* user_W   = (const float*)d_in[2];
    const float* item_W   = (const float*)d_in[3];
    const float* h        = (const float*)d_in[4];
    float* out = (float*)d_out;
    float* ws  = (float*)d_ws;

    gram_convert<<<NBI + NBU, 256, 0, stream>>>(uids, user_W, item_W, ws);
    pos_and_reduce<<<BATCH + 256, 256, 0, stream>>>(uids, pos_iids, user_W, h, ws);
    final_sum<<<1, 256, 0, stream>>>(ws, out);
}